// Round 1
// baseline (528.619 us; speedup 1.0000x reference)
//
#include <hip/hip_runtime.h>
#include <hip/hip_bf16.h>

#define NB   8
#define NS   5
#define NQ   128
#define TT   16
#define DD   2048
#define BK   128
#define LDK  (BK + 8)      // +8 bf16 pad -> row stride 272B, 2-way bank aliasing (free)
#define NROW 1024          // B*nq
#define LAMI 10.0f         // 1/LAM
#define LAMF 0.1f

typedef __attribute__((ext_vector_type(8))) short  short8;
typedef __attribute__((ext_vector_type(4))) float  float4v;
typedef __attribute__((ext_vector_type(4))) unsigned short ushort4v;

static __device__ __forceinline__ unsigned short f2bf(float f) {
    union { float f; unsigned int u; } c; c.f = f;
    unsigned int u = c.u;
    unsigned int r = u + 0x7fffu + ((u >> 16) & 1u);   // RNE
    return (unsigned short)(r >> 16);
}

// logaddexp(x,y) = max + log1p(exp(min-max)); log1p via __logf(1+t) (t<=1, fine here)
static __device__ __forceinline__ float lse2(float x, float y) {
    float mx = fmaxf(x, y), mn = fminf(x, y);
    return mx + __logf(1.0f + __expf(mn - mx));
}

__global__ __launch_bounds__(320) void
dist_dtw_kernel(const float* __restrict__ supp, const float* __restrict__ query,
                float* __restrict__ out_tam, float* __restrict__ t1w, float* __restrict__ t2w)
{
    __shared__ __align__(16) unsigned short sS[80 * LDK];  // supp bf16 chunk (5*16 rows)
    __shared__ __align__(16) unsigned short sQ[16 * LDK];  // query bf16 chunk
    __shared__ float ssq[96];                              // sumsq: rows 0..79 supp, 80..95 query
    __shared__ float distS[NS][TT][TT];
    __shared__ float tamv[16];

    const int tid  = threadIdx.x;
    const int blk  = blockIdx.x;          // b*128 + q
    const int wave = tid >> 6;            // 0..4 == s
    const int lane = tid & 63;
    const int fr   = lane & 15;
    const int quad = lane >> 4;

    const float* qbase = query + (size_t)blk * (TT * DD);
    const float* sbase = supp  + (size_t)(blk >> 7) * (NS * TT * DD);

    if (tid < 96) ssq[tid] = 0.0f;
    __syncthreads();

    float4v acc = {0.f, 0.f, 0.f, 0.f};

    for (int k0 = 0; k0 < DD; k0 += BK) {
        // stage query chunk: 16 rows x 32 float4
        for (int idx = tid; idx < 16 * (BK / 4); idx += 320) {
            int row = idx >> 5, c4 = idx & 31;
            float4 v = *reinterpret_cast<const float4*>(qbase + (size_t)row * DD + k0 + c4 * 4);
            ushort4v pv = { f2bf(v.x), f2bf(v.y), f2bf(v.z), f2bf(v.w) };
            *reinterpret_cast<ushort4v*>(&sQ[row * LDK + c4 * 4]) = pv;
            atomicAdd(&ssq[80 + row], v.x * v.x + v.y * v.y + v.z * v.z + v.w * v.w);
        }
        // stage supp chunk: 80 rows x 32 float4 (exactly 8 iters/thread)
        for (int idx = tid; idx < 80 * (BK / 4); idx += 320) {
            int row = idx >> 5, c4 = idx & 31;
            float4 v = *reinterpret_cast<const float4*>(sbase + (size_t)row * DD + k0 + c4 * 4);
            ushort4v pv = { f2bf(v.x), f2bf(v.y), f2bf(v.z), f2bf(v.w) };
            *reinterpret_cast<ushort4v*>(&sS[row * LDK + c4 * 4]) = pv;
            atomicAdd(&ssq[row], v.x * v.x + v.y * v.y + v.z * v.z + v.w * v.w);
        }
        __syncthreads();

        const unsigned short* arow = &sS[(wave * 16 + fr) * LDK];
        const unsigned short* brow = &sQ[fr * LDK];
        #pragma unroll
        for (int kk = 0; kk < BK; kk += 32) {
            short8 a = *reinterpret_cast<const short8*>(arow + kk + quad * 8);
            short8 b = *reinterpret_cast<const short8*>(brow + kk + quad * 8);
            acc = __builtin_amdgcn_mfma_f32_16x16x32_bf16(a, b, acc, 0, 0, 0);
        }
        __syncthreads();
    }

    // epilogue: dist[s][l][m] = 1 - dot / max(||s_l|| * ||q_m||, eps)
    {
        float qn = sqrtf(ssq[80 + fr]);
        #pragma unroll
        for (int r = 0; r < 4; ++r) {
            int l = quad * 4 + r;
            float denom = fmaxf(sqrtf(ssq[wave * 16 + l]) * qn, 1e-8f);
            distS[wave][l][fr] = 1.0f - acc[r] / denom;
        }
    }
    __syncthreads();

    // DTW: threads 0..9  ->  s = tid>>1, dir = tid&1
    if (tid < 10) {
        const int s   = tid >> 1;
        const int dir = tid & 1;
        const float* dp = &distS[s][0][0];

        float prev[18], cur[18];
        // row l = 0: cumsum of dist_pad[0]
        {
            int ll = dir ? 15 : 0;
            float drow[16];
            #pragma unroll
            for (int m = 0; m < 16; ++m) drow[m] = dp[ll * 16 + (dir ? 15 - m : m)];
            prev[0] = 0.0f;
            #pragma unroll
            for (int m = 1; m <= 16; ++m) prev[m] = prev[m - 1] + drow[m - 1];
            prev[17] = prev[16];
        }
        for (int l = 1; l < 16; ++l) {
            int ll = dir ? 15 - l : l;
            float drow[16];
            #pragma unroll
            for (int m = 0; m < 16; ++m) drow[m] = dp[ll * 16 + (dir ? 15 - m : m)];
            cur[0] = 0.0f;
            #pragma unroll
            for (int m = 1; m <= 17; ++m) {
                float diag = prev[m - 1], up = prev[m], left = cur[m - 1];
                float d = (m <= 16) ? drow[m - 1] : 0.0f;
                float val;
                if (m == 1 || m == 17) {
                    // sequential 3-way: s3 = lse(lse(-diag/L,-left/L), -up/L)
                    float a = -diag * LAMI, b = -left * LAMI, c = -up * LAMI;
                    float s3 = lse2(lse2(a, b), c);
                    val = -LAMF * s3 + d;
                } else {
                    float lo = fminf(diag, left), hi = fmaxf(diag, left);
                    val = lo - LAMF * __logf(1.0f + __expf((lo - hi) * LAMI)) + d;
                }
                cur[m] = val;
            }
            #pragma unroll
            for (int m = 0; m < 18; ++m) prev[m] = cur[m];
        }
        tamv[tid] = prev[17];
    }
    __syncthreads();

    if (tid < NS) {
        float t1 = tamv[2 * tid], t2 = tamv[2 * tid + 1];
        int n = blk * NS + tid;
        t1w[n] = t1;
        t2w[n] = t2;
        out_tam[n] = 0.5f * (t1 + t2);
    }
}

__global__ __launch_bounds__(1024) void
loss_kernel(const float* __restrict__ t1w, const float* __restrict__ t2w,
            const int* __restrict__ ys, float* __restrict__ out)
{
    __shared__ float red[16];
    const int row = threadIdx.x;   // 1024 rows, one per thread

    float t1[NS], t2[NS];
    #pragma unroll
    for (int s = 0; s < NS; ++s) { t1[s] = t1w[row * NS + s]; t2[s] = t2w[row * NS + s]; }
    const int y = ys[row];

    float mx1 = -t1[0], mx2 = -t2[0];
    #pragma unroll
    for (int s = 1; s < NS; ++s) { mx1 = fmaxf(mx1, -t1[s]); mx2 = fmaxf(mx2, -t2[s]); }
    float s1 = 0.f, s2 = 0.f;
    #pragma unroll
    for (int s = 0; s < NS; ++s) { s1 += __expf(-t1[s] - mx1); s2 += __expf(-t2[s] - mx2); }
    float lse1 = mx1 + __logf(s1);
    float lse2v = mx2 + __logf(s2);

    float ty1 = t1[0], ty2 = t2[0];
    #pragma unroll
    for (int s = 1; s < NS; ++s) { if (y == s) { ty1 = t1[s]; ty2 = t2[s]; } }

    float c = 0.5f * ((lse1 + ty1) + (lse2v + ty2));

    #pragma unroll
    for (int off = 32; off >= 1; off >>= 1) c += __shfl_down(c, off, 64);
    if ((row & 63) == 0) red[row >> 6] = c;
    __syncthreads();
    if (row == 0) {
        float tot = 0.f;
        #pragma unroll
        for (int i = 0; i < 16; ++i) tot += red[i];
        out[0] = tot * (1.0f / (float)NROW);
    }
}

extern "C" void kernel_launch(void* const* d_in, const int* in_sizes, int n_in,
                              void* d_out, int out_size, void* d_ws, size_t ws_size,
                              hipStream_t stream) {
    const float* supp  = (const float*)d_in[0];
    const float* query = (const float*)d_in[1];
    const int*   ys    = (const int*)d_in[2];
    float* out = (float*)d_out;

    float* t1w = (float*)d_ws;                 // 5120 f32
    float* t2w = t1w + NROW * NS;              // 5120 f32

    dist_dtw_kernel<<<NROW, 320, 0, stream>>>(supp, query, out + 1, t1w, t2w);
    loss_kernel<<<1, 1024, 0, stream>>>(t1w, t2w, ys, out);
}

// Round 2
// 256.357 us; speedup vs baseline: 2.0620x; 2.0620x over previous
//
#include <hip/hip_runtime.h>
#include <hip/hip_bf16.h>

#define NB   8
#define NS   5
#define NQ   128
#define TT   16
#define DD   2048
#define BK   64
#define LDK  72            // shorts; row stride 144B -> (fr+quad)%8 bank groups, 2-way = free
#define NROW 1024          // B*nq
#define NTH  384           // 6 waves
#define LAMI 10.0f         // 1/LAM
#define LAMF 0.1f

typedef __attribute__((ext_vector_type(8))) short  short8;
typedef __attribute__((ext_vector_type(4))) float  float4v;

// pack two f32 -> bf16x2 (RNE)
static __device__ __forceinline__ unsigned int f2bf2(float x, float y) {
    union { float f; unsigned int u; } a, b; a.f = x; b.f = y;
    unsigned int ra = a.u + 0x7fffu + ((a.u >> 16) & 1u);
    unsigned int rb = b.u + 0x7fffu + ((b.u >> 16) & 1u);
    return (ra >> 16) | (rb & 0xffff0000u);
}

static __device__ __forceinline__ float lse2(float x, float y) {
    float mx = fmaxf(x, y), mn = fminf(x, y);
    return mx + __logf(1.0f + __expf(mn - mx));
}

__global__ __launch_bounds__(NTH, 6) void
dist_dtw_kernel(const float* __restrict__ supp, const float* __restrict__ query,
                float* __restrict__ out_tam, float* __restrict__ t1w, float* __restrict__ t2w)
{
    __shared__ __align__(16) unsigned short sAB[2][96 * LDK]; // rows 0..79 supp, 80..95 query
    __shared__ float ssq[96];
    __shared__ float distS[NS][TT][TT];
    __shared__ float tamv[16];

    const int tid  = threadIdx.x;
    const int blk  = blockIdx.x;          // b*128 + q
    const int wave = tid >> 6;            // 0..5 (0..4 = s for MFMA)
    const int lane = tid & 63;
    const int fr   = lane & 15;
    const int quad = lane >> 4;

    const float* qbase = query + (size_t)blk * (TT * DD);
    const float* sbase = supp  + (size_t)(blk >> 7) * (NS * TT * DD);

    // fixed per-thread staging assignment: idx = j*NTH + tid -> (row, col)
    const float* gp[4];
    int lo[4];
    int rowj[4];
    #pragma unroll
    for (int j = 0; j < 4; ++j) {
        int idx = j * NTH + tid;
        int row = idx >> 4;          // 0..95 (16 float4 per row-chunk)
        int col = idx & 15;
        rowj[j] = row;
        gp[j] = (row < 80 ? sbase + (size_t)row * DD
                          : qbase + (size_t)(row - 80) * DD) + col * 4;
        lo[j] = row * LDK + col * 4;
    }

    float4 regs[2][4];
    #pragma unroll
    for (int j = 0; j < 4; ++j) regs[0][j] = *reinterpret_cast<const float4*>(gp[j]);

    float ss[4] = {0.f, 0.f, 0.f, 0.f};
    float4v acc = {0.f, 0.f, 0.f, 0.f};

    #pragma unroll 2
    for (int k = 0; k < DD / BK; ++k) {
        const int buf = k & 1;
        // issue next chunk's loads first (independent, stays in flight across barrier/MFMA)
        if (k < DD / BK - 1) {
            #pragma unroll
            for (int j = 0; j < 4; ++j)
                regs[buf ^ 1][j] = *reinterpret_cast<const float4*>(gp[j] + (k + 1) * BK);
        }
        // convert current chunk -> LDS, accumulate sumsq in registers
        #pragma unroll
        for (int j = 0; j < 4; ++j) {
            float4 v = regs[buf][j];
            uint2 pv = { f2bf2(v.x, v.y), f2bf2(v.z, v.w) };
            *reinterpret_cast<uint2*>(&sAB[buf][lo[j]]) = pv;
            ss[j] += v.x * v.x + v.y * v.y + v.z * v.z + v.w * v.w;
        }
        __syncthreads();
        if (wave < NS) {
            const unsigned short* arow = &sAB[buf][(wave * 16 + fr) * LDK];
            const unsigned short* brow = &sAB[buf][(80 + fr) * LDK];
            short8 a0 = *reinterpret_cast<const short8*>(arow + quad * 8);
            short8 b0 = *reinterpret_cast<const short8*>(brow + quad * 8);
            acc = __builtin_amdgcn_mfma_f32_16x16x32_bf16(a0, b0, acc, 0, 0, 0);
            short8 a1 = *reinterpret_cast<const short8*>(arow + 32 + quad * 8);
            short8 b1 = *reinterpret_cast<const short8*>(brow + 32 + quad * 8);
            acc = __builtin_amdgcn_mfma_f32_16x16x32_bf16(a1, b1, acc, 0, 0, 0);
        }
        // no second barrier: double-buffered (iter k+1 stores buf^1, last read at iter k-1,
        // ordered by barrier k for every wave)
    }

    // sumsq: 16 consecutive tids (same j) hold the 16 col-slots of one row
    #pragma unroll
    for (int j = 0; j < 4; ++j) {
        float v = ss[j];
        v += __shfl_xor(v, 1, 16);
        v += __shfl_xor(v, 2, 16);
        v += __shfl_xor(v, 4, 16);
        v += __shfl_xor(v, 8, 16);
        if ((tid & 15) == 0) ssq[rowj[j]] = v;   // each row written exactly once
    }
    __syncthreads();

    // epilogue: dist[s][l][m] = 1 - dot / max(||s_l||*||q_m||, eps)
    if (wave < NS) {
        float qn = sqrtf(ssq[80 + fr]);
        #pragma unroll
        for (int r = 0; r < 4; ++r) {
            int l = quad * 4 + r;
            float denom = fmaxf(sqrtf(ssq[wave * 16 + l]) * qn, 1e-8f);
            distS[wave][l][fr] = 1.0f - acc[r] / denom;
        }
    }
    __syncthreads();

    // DTW: anti-diagonal wavefront. wave w = support s; lanes 0..17 dir=0, 32..49 dir=1.
    // Lane g holds column m=g of the (16 x 18) opt grid. Cell (l,g) computed at step t=l+g.
    if (wave < NS && (lane & 31) <= 17) {
        const int g   = lane & 31;
        const int dir = lane >> 5;
        const int s   = wave;
        float val = 0.f, vprev = 0.f;   // lane g: last two computed rows of column g
        #pragma unroll
        for (int t = 1; t <= 32; ++t) {
            float left = __shfl_up(val,   1, 32);  // (l,   g-1)
            float diag = __shfl_up(vprev, 1, 32);  // (l-1, g-1)
            int l = t - g;
            if (g >= 1 && l >= 0 && l <= 15) {
                float d = 0.f;
                if (g <= 16) d = dir ? distS[s][15 - l][16 - g] : distS[s][l][g - 1];
                float nv;
                if (l == 0) {
                    nv = left + d;                                   // row-0 cumsum
                } else if (g == 1 || g == 17) {
                    nv = -LAMF * lse2(lse2(-diag * LAMI, -left * LAMI), -val * LAMI) + d;
                } else {
                    float lo2 = fminf(diag, left), hi2 = fmaxf(diag, left);
                    nv = lo2 - LAMF * __logf(1.0f + __expf((lo2 - hi2) * LAMI)) + d;
                }
                vprev = val; val = nv;
            }
        }
        if (g == 17) tamv[s * 2 + dir] = val;      // opt[15][17]
    }
    __syncthreads();

    if (tid < NS) {
        float t1 = tamv[2 * tid], t2 = tamv[2 * tid + 1];
        int n = blk * NS + tid;
        t1w[n] = t1;
        t2w[n] = t2;
        out_tam[n] = 0.5f * (t1 + t2);
    }
}

__global__ __launch_bounds__(1024) void
loss_kernel(const float* __restrict__ t1w, const float* __restrict__ t2w,
            const int* __restrict__ ys, float* __restrict__ out)
{
    __shared__ float red[16];
    const int row = threadIdx.x;

    float t1[NS], t2[NS];
    #pragma unroll
    for (int s = 0; s < NS; ++s) { t1[s] = t1w[row * NS + s]; t2[s] = t2w[row * NS + s]; }
    const int y = ys[row];

    float mx1 = -t1[0], mx2 = -t2[0];
    #pragma unroll
    for (int s = 1; s < NS; ++s) { mx1 = fmaxf(mx1, -t1[s]); mx2 = fmaxf(mx2, -t2[s]); }
    float s1 = 0.f, s2 = 0.f;
    #pragma unroll
    for (int s = 0; s < NS; ++s) { s1 += __expf(-t1[s] - mx1); s2 += __expf(-t2[s] - mx2); }
    float lse1  = mx1 + __logf(s1);
    float lse2v = mx2 + __logf(s2);

    float ty1 = t1[0], ty2 = t2[0];
    #pragma unroll
    for (int s = 1; s < NS; ++s) { if (y == s) { ty1 = t1[s]; ty2 = t2[s]; } }

    float c = 0.5f * ((lse1 + ty1) + (lse2v + ty2));

    #pragma unroll
    for (int off = 32; off >= 1; off >>= 1) c += __shfl_down(c, off, 64);
    if ((row & 63) == 0) red[row >> 6] = c;
    __syncthreads();
    if (row == 0) {
        float tot = 0.f;
        #pragma unroll
        for (int i = 0; i < 16; ++i) tot += red[i];
        out[0] = tot * (1.0f / (float)NROW);
    }
}

extern "C" void kernel_launch(void* const* d_in, const int* in_sizes, int n_in,
                              void* d_out, int out_size, void* d_ws, size_t ws_size,
                              hipStream_t stream) {
    const float* supp  = (const float*)d_in[0];
    const float* query = (const float*)d_in[1];
    const int*   ys    = (const int*)d_in[2];
    float* out = (float*)d_out;

    float* t1w = (float*)d_ws;                 // 5120 f32
    float* t2w = t1w + NROW * NS;              // 5120 f32

    dist_dtw_kernel<<<NROW, NTH, 0, stream>>>(supp, query, out + 1, t1w, t2w);
    loss_kernel<<<1, 1024, 0, stream>>>(t1w, t2w, ys, out);
}